// Round 12
// baseline (224.173 us; speedup 1.0000x reference)
//
#include <hip/hip_runtime.h>

// ---------------------------------------------------------------------------
// EncoderBlock: pre-LN transformer block, B=2 S=2048 D=1024 H=16 dk=64 F=4096
// R12: big GEMMs re-tiled 256x256 -> 256x128 (8 waves 4Mx2N, wave=64x64),
//     2-slot LDS ring (48-64KB vs 128KB) + launch_bounds(512,4) -> 2 blocks/CU
//     (4 waves/SIMD, was 1 block/2 waves); grids now cover all CUs (QKV 384,
//     FFN1 512 blocks). gemm128sq also 2-slot (32KB, (256,4)). Attn unchanged.
// Workspace layout (80 MB used):
//   [0,6M)    wqkv bf16 (dead after QKV) -> ml f32 (1MB) -> p0 bf16 for FFN2
//   [6M,8M)   wo bf16
//   [8M,16M)  w1 bf16
//   [16M,24M) w2 bf16
//   [24M,32M) xn bf16 (LN out; dead after FFN1) -> p1 bf16 for FFN2
//   [32M,40M) q bf16 [B,H,S,64] (scaled by 0.125*log2e)  } reused as h for FFN1
//   [40M,48M) k bf16 [B,H,S,64]                          }
//   [48M,56M) vT bf16 [B,H,64,S]                         }
//   [56M,64M) ctx bf16 flat [B*S,1024]                   }
//   [64M,80M) opart bf16 (attn partials; dead after merge) -> x1 fp32
// ---------------------------------------------------------------------------

typedef __bf16 bf16_t;
typedef __attribute__((ext_vector_type(8))) __bf16 bf16x8;
typedef __attribute__((ext_vector_type(4))) __bf16 bf16x4;
typedef __attribute__((ext_vector_type(2))) __bf16 bf16x2;
typedef __attribute__((ext_vector_type(4))) float f32x4;
typedef __attribute__((ext_vector_type(16))) float f32x16;
typedef __attribute__((ext_vector_type(2))) unsigned uint32x2;
typedef __attribute__((ext_vector_type(4))) unsigned uint32x4;

#define MB (1024ull * 1024ull)
#define QSCALE 0.18033688011112043f /* 0.125 * log2(e) */

__device__ __forceinline__ void gload_lds16(const bf16_t* g, bf16_t* l) {
    __builtin_amdgcn_global_load_lds(
        (const __attribute__((address_space(1))) void*)g,
        (__attribute__((address_space(3))) void*)l, 16, 0, 0);
}

// Bank-slot XOR for BK=32 (64B) LDS rows: chunk ^= (row>>1)&3 (2-way max).
__device__ __forceinline__ int bsw(int row) { return (row >> 1) & 3; }

// XOR swizzle for 64-col bf16 LDS tiles (128B rows). (attn + v-transpose)
__device__ __forceinline__ int swz(int row, int col) {
    return row * 64 + ((((col >> 3) ^ row) & 7) << 3) + (col & 7);
}

__device__ __forceinline__ unsigned cvtpk(float a, float b) {
    bf16x2 v = {(__bf16)a, (__bf16)b};
    return __builtin_bit_cast(unsigned, v);
}

// --------------------------- fp32 -> bf16 convert (merged) ------------------
__global__ __launch_bounds__(256) void cvt_all(
    const float* __restrict__ wq, const float* __restrict__ wk,
    const float* __restrict__ wv, const float* __restrict__ wo,
    const float* __restrict__ w1, const float* __restrict__ w2,
    bf16_t* __restrict__ wqkv, bf16_t* __restrict__ wob, bf16_t* __restrict__ w1b,
    bf16_t* __restrict__ w2b) {
    const int b = blockIdx.x, t = threadIdx.x;
    const float* in;
    bf16_t* out;
    int i;
    if (b < 1024) { in = wq; out = wqkv; i = b * 256 + t; }
    else if (b < 2048) { in = wk; out = wqkv + 1048576; i = (b - 1024) * 256 + t; }
    else if (b < 3072) { in = wv; out = wqkv + 2097152; i = (b - 2048) * 256 + t; }
    else if (b < 4096) { in = wo; out = wob; i = (b - 3072) * 256 + t; }
    else if (b < 8192) { in = w1; out = w1b; i = (b - 4096) * 256 + t; }
    else { in = w2; out = w2b; i = (b - 8192) * 256 + t; }
    float4 v = ((const float4*)in)[i];
    bf16x4 o = {(__bf16)v.x, (__bf16)v.y, (__bf16)v.z, (__bf16)v.w};
    ((bf16x4*)out)[i] = o;
}

// --------------------------- LayerNorm (torch-style) ------------------------
__global__ __launch_bounds__(256) void ln_kernel(const float* __restrict__ x,
                                                 bf16_t* __restrict__ out,
                                                 const float* __restrict__ gamma,
                                                 const float* __restrict__ beta) {
    const int lane = threadIdx.x & 63;
    const int row = blockIdx.x * 4 + (threadIdx.x >> 6);
    const float* xr = x + (size_t)row * 1024;
    float4 v[4];
    float s = 0.f;
#pragma unroll
    for (int i = 0; i < 4; ++i) {
        v[i] = ((const float4*)xr)[i * 64 + lane];
        s += v[i].x + v[i].y + v[i].z + v[i].w;
    }
#pragma unroll
    for (int o = 32; o; o >>= 1) s += __shfl_xor(s, o);
    float mean = s * (1.f / 1024.f);
    float vs = 0.f;
#pragma unroll
    for (int i = 0; i < 4; ++i) {
        float a = v[i].x - mean, b = v[i].y - mean, c = v[i].z - mean, d = v[i].w - mean;
        vs += a * a + b * b + c * c + d * d;
    }
#pragma unroll
    for (int o = 32; o; o >>= 1) vs += __shfl_xor(vs, o);
    float inv = 1.f / (sqrtf(vs * (1.f / 1023.f)) + 1e-5f);
    float g = gamma[0] * inv, bb = beta[0];
    bf16_t* orow = out + (size_t)row * 1024;
#pragma unroll
    for (int i = 0; i < 4; ++i) {
        bf16x4 ov = {(__bf16)((v[i].x - mean) * g + bb), (__bf16)((v[i].y - mean) * g + bb),
                     (__bf16)((v[i].z - mean) * g + bb), (__bf16)((v[i].w - mean) * g + bb)};
        *(bf16x4*)(orow + (i * 64 + lane) * 4) = ov;
    }
}

// -------------- Pipelined 256x128 GEMM (C = A @ W^T), 8 waves ---------------
// waves 4Mx2N, wave=64x64 (16 MFMA : 8 ds_read/iter). BK=32, 2-slot ring,
// counted vmcnt(3). A staged in split-half linear layout (wave-uniform dest).
// KERN 0: QKV (N=3072 via bn 0..23): q/k head-major + scale, v transposed.
// KERN 1: FFN1 +bias +relu -> bf16 [4096,4096].
template <int KERN>
__global__ __launch_bounds__(512, 4) void gemmBig(
    const bf16_t* __restrict__ A, const bf16_t* __restrict__ Bw, int K,
    const float* __restrict__ bias0, const float* __restrict__ bias1,
    const float* __restrict__ bias2, void* __restrict__ o0, void* __restrict__ o1,
    void* __restrict__ o2) {
    __shared__ bf16_t L[KERN == 0 ? 32768 : 24576];  // ring 2x12288; +transpose
    const int t = threadIdx.x, lane = t & 63, w = t >> 6;
    const int wr = w >> 1, wc = w & 1;
    const int l15 = lane & 15, l4 = lane >> 4;
    const int bm = blockIdx.x, bn = blockIdx.y;
    const int NT = K >> 5;
    const bf16_t* Ab = A + (size_t)bm * 256 * K;
    const bf16_t* Bb = Bw + (size_t)bn * 128 * K;
    // staging roles
    const int arow = t >> 1, ac0 = t & 1;      // A: rows 0..255, chunks {ac0, ac0+2}
    const int brow = t >> 2, bc = t & 3;       // B: rows 0..127, chunk bc
    f32x4 acc[4][4] = {};

    auto STAGE = [&](int tt) {
        bf16_t* s = L + (tt & 1) * 12288;
        const int kb = tt * 32;
        // A inst0: chunk ac0 -> pos t ; inst1: chunk ac0+2 -> pos 512+t
        gload_lds16(Ab + (size_t)arow * K + kb + ((ac0 ^ bsw(arow)) << 3), s + t * 8);
        gload_lds16(Ab + (size_t)arow * K + kb + (((ac0 + 2) ^ bsw(arow)) << 3),
                    s + 4096 + t * 8);
        gload_lds16(Bb + (size_t)brow * K + kb + ((bc ^ bsw(brow)) << 3), s + 8192 + t * 8);
    };

    STAGE(0);
    for (int tt = 0; tt < NT; ++tt) {
        if (tt + 1 < NT) {
            STAGE(tt + 1);
            asm volatile("s_waitcnt vmcnt(3)" ::: "memory");
        } else {
            asm volatile("s_waitcnt vmcnt(0)" ::: "memory");
        }
        __builtin_amdgcn_s_barrier();
        bf16_t* s = L + (tt & 1) * 12288;
        bf16x8 af[4], bfr[4];
#pragma unroll
        for (int m = 0; m < 4; ++m) {
            int row = wr * 64 + m * 16 + l15;
            int ch = l4 ^ bsw(row);
            af[m] = *(const bf16x8*)(s + ((ch >> 1) << 12) + row * 16 + ((ch & 1) << 3));
        }
#pragma unroll
        for (int n = 0; n < 4; ++n) {
            int row = wc * 64 + n * 16 + l15;
            int ch = l4 ^ bsw(row);
            bfr[n] = *(const bf16x8*)(s + 8192 + row * 32 + (ch << 3));
        }
        __builtin_amdgcn_s_setprio(1);
#pragma unroll
        for (int m = 0; m < 4; ++m)
#pragma unroll
            for (int n = 0; n < 4; ++n)
                acc[m][n] = __builtin_amdgcn_mfma_f32_16x16x32_bf16(af[m], bfr[n], acc[m][n],
                                                                   0, 0, 0);
        __builtin_amdgcn_s_setprio(0);
        __builtin_amdgcn_s_barrier();
    }

    if (KERN == 1) {
        const int colb = bn * 128 + wc * 64;
        float bb[4];
#pragma unroll
        for (int n = 0; n < 4; ++n) bb[n] = bias0[colb + n * 16 + l15];
#pragma unroll
        for (int m = 0; m < 4; ++m) {
            const int row0 = bm * 256 + wr * 64 + m * 16 + (l4 << 2);
#pragma unroll
            for (int n = 0; n < 4; ++n)
#pragma unroll
                for (int j = 0; j < 4; ++j) {
                    float v = acc[m][n][j] + bb[n];
                    ((bf16_t*)o0)[(size_t)(row0 + j) * 4096 + colb + n * 16 + l15] =
                        (bf16_t)(v > 0.f ? v : 0.f);
                }
        }
        return;
    }
    // KERN 0: QKV epilogue. Each wave owns one head's 64 cols x 64 rows.
    if (bn < 16) {
        const bool isq = bn < 8;
        const float* bias = isq ? bias0 : bias1;
        const int head = ((bn & 7) << 1) + wc;
        bf16_t* dst = (bf16_t*)(isq ? o0 : o1);
        float bb[4];
#pragma unroll
        for (int n = 0; n < 4; ++n) bb[n] = bias[head * 64 + n * 16 + l15];
#pragma unroll
        for (int m = 0; m < 4; ++m)
#pragma unroll
            for (int n = 0; n < 4; ++n)
#pragma unroll
                for (int j = 0; j < 4; ++j) {
                    int srw = bm * 256 + wr * 64 + m * 16 + (l4 << 2) + j;
                    int b = srw >> 11, ss = srw & 2047;
                    float v = acc[m][n][j] + bb[n];
                    if (isq) v *= QSCALE;
                    dst[((size_t)(b * 16 + head) << 17) + ((size_t)ss << 6) + n * 16 + l15] =
                        (bf16_t)v;
                }
    } else {
        // v: per-wave 64x64 LDS transpose -> [B,H,64,S] coalesced
        const int head = ((bn - 16) << 1) + wc;
        const int srw0 = bm * 256 + wr * 64;
        const int b = srw0 >> 11, sb = srw0 & 2047;
        bf16_t* P = L + w * 4096;  // 8KB/wave
        float bb[4];
#pragma unroll
        for (int n = 0; n < 4; ++n) bb[n] = bias2[head * 64 + n * 16 + l15];
#pragma unroll
        for (int m = 0; m < 4; ++m)
#pragma unroll
            for (int n = 0; n < 4; ++n) {
                int d = n * 16 + l15;
#pragma unroll
                for (int j = 0; j < 4; ++j) {
                    int sl = m * 16 + (l4 << 2) + j;
                    P[swz(d, sl)] = (bf16_t)(acc[m][n][j] + bb[n]);
                }
            }
#pragma unroll
        for (int p = 0; p < 8; ++p) {
            int id = p * 64 + lane;
            int d = id >> 3, c8 = (id & 7) * 8;
            bf16x8 vv = *(const bf16x8*)(P + swz(d, c8));
            *(bf16x8*)((bf16_t*)o2 + (((size_t)((b * 16 + head) * 64 + d)) << 11) + sb + c8) =
                vv;
        }
    }
}

// ------------- Pipelined 128x128 GEMM, wave=64x64 (C = A @ W^T) -------------
// 2-slot ring (32KB), counted vmcnt(4). SPLIT=0: +bias +resid -> fp32.
// SPLIT=1: K-split via blockIdx.z, raw partial -> bf16.
template <int SPLIT>
__global__ __launch_bounds__(256, 4) void gemm128sq(
    const bf16_t* __restrict__ A, const bf16_t* __restrict__ Bw, int stride, int Ks,
    const float* __restrict__ bias, const float* __restrict__ resid,
    void* __restrict__ o0, void* __restrict__ o1) {
    __shared__ bf16_t L[2 * 8192];  // 2 slots x (A 128x32 + B 128x32) = 32KB
    const int t = threadIdx.x, lane = t & 63, w = t >> 6;
    const int wr = w >> 1, wc = w & 1;
    const int l15 = lane & 15, l4 = lane >> 4;
    const int bm = blockIdx.x, bn = blockIdx.y;
    const int NT = Ks >> 5;
    const size_t kofs = SPLIT ? (size_t)blockIdx.z * Ks : 0;
    const bf16_t* Ab = A + (size_t)bm * 128 * stride + kofs;
    const bf16_t* Bb = Bw + (size_t)bn * 128 * stride + kofs;
    const int srow = t >> 2, pcol = (t & 3);
    f32x4 acc[4][4] = {};

    auto STAGE = [&](int tt) {
        bf16_t* s = L + (tt & 1) * 8192;
        const int kb = tt * 32;
#pragma unroll
        for (int i = 0; i < 2; ++i) {
            int row = i * 64 + srow;
            int lcol = (pcol ^ bsw(row)) << 3;
            gload_lds16(Ab + (size_t)row * stride + kb + lcol, s + i * 2048 + t * 8);
            gload_lds16(Bb + (size_t)row * stride + kb + lcol, s + 4096 + i * 2048 + t * 8);
        }
    };

    STAGE(0);
    for (int tt = 0; tt < NT; ++tt) {
        if (tt + 1 < NT) {
            STAGE(tt + 1);
            asm volatile("s_waitcnt vmcnt(4)" ::: "memory");
        } else {
            asm volatile("s_waitcnt vmcnt(0)" ::: "memory");
        }
        __builtin_amdgcn_s_barrier();
        bf16_t* s = L + (tt & 1) * 8192;
        bf16x8 af[4], bfr[4];
#pragma unroll
        for (int m = 0; m < 4; ++m) {
            int row = wr * 64 + m * 16 + l15;
            af[m] = *(const bf16x8*)(s + row * 32 + (((l4 ^ bsw(row))) << 3));
        }
#pragma unroll
        for (int n = 0; n < 4; ++n) {
            int row = wc * 64 + n * 16 + l15;
            bfr[n] = *(const bf16x8*)(s + 4096 + row * 32 + (((l4 ^ bsw(row))) << 3));
        }
        __builtin_amdgcn_s_setprio(1);
#pragma unroll
        for (int m = 0; m < 4; ++m)
#pragma unroll
            for (int n = 0; n < 4; ++n)
                acc[m][n] = __builtin_amdgcn_mfma_f32_16x16x32_bf16(af[m], bfr[n], acc[m][n],
                                                                   0, 0, 0);
        __builtin_amdgcn_s_setprio(0);
        __builtin_amdgcn_s_barrier();
    }

#pragma unroll
    for (int m = 0; m < 4; ++m) {
        const int row0 = bm * 128 + wr * 64 + m * 16 + (l4 << 2);
#pragma unroll
        for (int n = 0; n < 4; ++n) {
            const int col = bn * 128 + wc * 64 + n * 16 + l15;
#pragma unroll
            for (int j = 0; j < 4; ++j) {
                const int row = row0 + j;
                if (SPLIT == 0) {
                    ((float*)o0)[(size_t)row * 1024 + col] =
                        resid[(size_t)row * 1024 + col] + acc[m][n][j] + bias[col];
                } else {
                    bf16_t* po = (bf16_t*)(blockIdx.z ? o1 : o0);
                    po[(size_t)row * 1024 + col] = (bf16_t)acc[m][n][j];
                }
            }
        }
    }
}

// ---- FFN2 combine: out = p0 + p1 + resid + bias (fp32), 4096x1024 ----------
__global__ __launch_bounds__(256) void ffn2_combine(
    const bf16_t* __restrict__ p0, const bf16_t* __restrict__ p1,
    const float* __restrict__ resid, const float* __restrict__ bias,
    float* __restrict__ out) {
    int i = blockIdx.x * 256 + threadIdx.x;  // float4 index, 1M total
    float4 r = ((const float4*)resid)[i];
    bf16x4 a = ((const bf16x4*)p0)[i];
    bf16x4 b = ((const bf16x4*)p1)[i];
    float4 bs = ((const float4*)bias)[i & 255];
    float4 o;
    o.x = r.x + (float)a.x + (float)b.x + bs.x;
    o.y = r.y + (float)a.y + (float)b.y + bs.y;
    o.z = r.z + (float)a.z + (float)b.z + bs.z;
    o.w = r.w + (float)a.w + (float)b.w + bs.w;
    ((float4*)out)[i] = o;
}

// --------------------- Flash attention split (R11) --------------------------
__global__ __launch_bounds__(256, 4) void attn_split(const bf16_t* __restrict__ q,
                                                     const bf16_t* __restrict__ k,
                                                     const bf16_t* __restrict__ vt,
                                                     bf16_t* __restrict__ opart,
                                                     float2* __restrict__ ml) {
    __shared__ bf16_t Kl[2][64 * 64];
    __shared__ bf16_t Vl[2][64 * 64];
    const int t = threadIdx.x, lane = t & 63, w = t >> 6;
    const int bid = blockIdx.x;
    const int xcd = bid & 7, j = bid >> 3;
    const int bh = xcd + ((j >> 5) << 3);
    const int qx = (j & 31) >> 1;
    const int half = j & 1;
    const int sbase = half << 10;
    const bf16_t* qg = q + (size_t)bh * 2048 * 64;
    const bf16_t* kg = k + (size_t)bh * 2048 * 64;
    const bf16_t* vg = vt + (size_t)bh * 64 * 2048;
    const int l31 = lane & 31, h = lane >> 5;
    const int rowl = w * 32 + l31;
    const int qrow = qx * 128 + rowl;
    const int prow = t >> 3, p = t & 7;
    const int sc = ((p ^ prow) & 7) * 8;

    bf16x8 qf[4];
#pragma unroll
    for (int kd = 0; kd < 4; ++kd)
        qf[kd] = *(const bf16x8*)(qg + (size_t)qrow * 64 + kd * 16 + h * 8);

    f32x16 o0 = {}, o1 = {};
    float mi = -1e30f, li = 0.f;

    auto STAGE = [&](int tt) {
        bf16_t* kd_ = Kl[tt & 1];
        bf16_t* vd_ = Vl[tt & 1];
        const int kb = sbase + tt * 64;
        gload_lds16(kg + (size_t)(kb + prow) * 64 + sc, kd_ + t * 8);
        gload_lds16(kg + (size_t)(kb + prow + 32) * 64 + sc, kd_ + 2048 + t * 8);
        gload_lds16(vg + (size_t)prow * 2048 + kb + sc, vd_ + t * 8);
        gload_lds16(vg + (size_t)(prow + 32) * 2048 + kb + sc, vd_ + 2048 + t * 8);
    };

    STAGE(0);
    const int NT = 16;
    for (int tt = 0; tt < NT; ++tt) {
        if (tt + 1 < NT) {
            STAGE(tt + 1);
            asm volatile("s_waitcnt vmcnt(4)" ::: "memory");
        } else {
            asm volatile("s_waitcnt vmcnt(0)" ::: "memory");
        }
        __builtin_amdgcn_s_barrier();
        const bf16_t* Kb = Kl[tt & 1];
        const bf16_t* Vb = Vl[tt & 1];
        f32x16 sT0 = {}, sT1 = {};
        __builtin_amdgcn_s_setprio(1);
#pragma unroll
        for (int kd = 0; kd < 4; ++kd) {
            bf16x8 ka0 = *(const bf16x8*)(Kb + swz(l31, kd * 16 + h * 8));
            bf16x8 ka1 = *(const bf16x8*)(Kb + swz(32 + l31, kd * 16 + h * 8));
            sT0 = __builtin_amdgcn_mfma_f32_32x32x16_bf16(ka0, qf[kd], sT0, 0, 0, 0);
            sT1 = __builtin_amdgcn_mfma_f32_32x32x16_bf16(ka1, qf[kd], sT1, 0, 0, 0);
        }
        __builtin_amdgcn_s_setprio(0);
        float pm[16];
#pragma unroll
        for (int i = 0; i < 16; ++i) pm[i] = fmaxf(sT0[i], sT1[i]);
#pragma unroll
        for (int st = 8; st; st >>= 1)
#pragma unroll
            for (int i = 0; i < st; ++i) pm[i] = fmaxf(pm[i], pm[i + st]);
        float mx = fmaxf(pm[0], __shfl_xor(pm[0], 32));
        if (!__all(mx <= mi + 8.f)) {
            float mn = fmaxf(mi, mx);
            float al = __builtin_amdgcn_exp2f(mi - mn);
            mi = mn;
            li *= al;
            o0 *= al;
            o1 *= al;
        }
        f32x16 e0, e1;
#pragma unroll
        for (int i = 0; i < 16; ++i) e0[i] = __builtin_amdgcn_exp2f(sT0[i] - mi);
#pragma unroll
        for (int i = 0; i < 16; ++i) e1[i] = __builtin_amdgcn_exp2f(sT1[i] - mi);
        float ps[16];
#pragma unroll
        for (int i = 0; i < 16; ++i) ps[i] = e0[i] + e1[i];
#pragma unroll
        for (int st = 8; st; st >>= 1)
#pragma unroll
            for (int i = 0; i < st; ++i) ps[i] += ps[i + st];
        li += ps[0] + __shfl_xor(ps[0], 32);
        bf16x8 pa[4];
#pragma unroll
        for (int kd = 0; kd < 4; ++kd) {
            const f32x16& e = (kd < 2) ? e0 : e1;
            const int R0l = 8 * (kd & 1);
            const int R0h = R0l + 4;
            unsigned U0 = cvtpk(e[R0l + 0], e[R0l + 1]);
            unsigned V0 = cvtpk(e[R0l + 2], e[R0l + 3]);
            unsigned U1 = cvtpk(e[R0h + 0], e[R0h + 1]);
            unsigned V1 = cvtpk(e[R0h + 2], e[R0h + 3]);
            uint32x2 ru = __builtin_amdgcn_permlane32_swap(U0, U1, false, false);
            uint32x2 rv = __builtin_amdgcn_permlane32_swap(V0, V1, false, false);
            uint32x4 pw = {ru.x, rv.x, ru.y, rv.y};
            pa[kd] = __builtin_bit_cast(bf16x8, pw);
        }
        __builtin_amdgcn_s_setprio(1);
#pragma unroll
        for (int kd = 0; kd < 4; ++kd) {
            bf16x8 va0 = *(const bf16x8*)(Vb + swz(l31, kd * 16 + h * 8));
            bf16x8 va1 = *(const bf16x8*)(Vb + swz(32 + l31, kd * 16 + h * 8));
            o0 = __builtin_amdgcn_mfma_f32_32x32x16_bf16(va0, pa[kd], o0, 0, 0, 0);
            o1 = __builtin_amdgcn_mfma_f32_32x32x16_bf16(va1, pa[kd], o1, 0, 0, 0);
        }
        __builtin_amdgcn_s_setprio(0);
        __builtin_amdgcn_s_barrier();
    }
    const int combo = bh * 16 + qx;
    bf16_t* op = opart + ((size_t)half << 22) + (size_t)combo * 8192 + (size_t)rowl * 64;
#pragma unroll
    for (int g = 0; g < 4; ++g) {
        bf16x4 ov0 = {(__bf16)o0[4 * g + 0], (__bf16)o0[4 * g + 1], (__bf16)o0[4 * g + 2],
                      (__bf16)o0[4 * g + 3]};
        *(bf16x4*)(op + 8 * g + 4 * h) = ov0;
        bf16x4 ov1 = {(__bf16)o1[4 * g + 0], (__bf16)o1[4 * g + 1], (__bf16)o1[4 * g + 2],
                      (__bf16)o1[4 * g + 3]};
        *(bf16x4*)(op + 32 + 8 * g + 4 * h) = ov1;
    }
    if (h == 0) ml[((size_t)half * 512 + combo) * 128 + rowl] = make_float2(mi, li);
}

// ---- attn merge ------------------------------------------------------------
__global__ __launch_bounds__(256) void attn_merge(const bf16_t* __restrict__ opart,
                                                  const float2* __restrict__ ml,
                                                  bf16_t* __restrict__ ctx) {
    const int combo = blockIdx.x >> 2;
    const int row = (blockIdx.x & 3) * 32 + (threadIdx.x >> 3);
    const int d8 = (threadIdx.x & 7) * 8;
    float2 a = ml[(size_t)combo * 128 + row];
    float2 b = ml[(size_t)(512 + combo) * 128 + row];
    float m = fmaxf(a.x, b.x);
    float ea = __builtin_amdgcn_exp2f(a.x - m), eb = __builtin_amdgcn_exp2f(b.x - m);
    float inv = 1.f / (a.y * ea + b.y * eb);
    float ia = ea * inv, ib = eb * inv;
    size_t po = (size_t)combo * 8192 + (size_t)row * 64 + d8;
    bf16x8 u = *(const bf16x8*)(opart + po);
    bf16x8 v = *(const bf16x8*)(opart + (1ull << 22) + po);
    bf16x8 o;
#pragma unroll
    for (int jj = 0; jj < 8; ++jj) o[jj] = (__bf16)((float)u[jj] * ia + (float)v[jj] * ib);
    const int bh = combo >> 4, qx = combo & 15;
    const int rg = qx * 128 + row;
    *(bf16x8*)(ctx + ((size_t)(bh >> 4) * 2048 + rg) * 1024 + (bh & 15) * 64 + d8) = o;
}

// ---------------------------------------------------------------------------
extern "C" void kernel_launch(void* const* d_in, const int* in_sizes, int n_in,
                              void* d_out, int out_size, void* d_ws, size_t ws_size,
                              hipStream_t stream) {
    const float* x = (const float*)d_in[0];
    const float* wq = (const float*)d_in[2];
    const float* bq = (const float*)d_in[3];
    const float* wk = (const float*)d_in[4];
    const float* bk = (const float*)d_in[5];
    const float* wv = (const float*)d_in[6];
    const float* bv = (const float*)d_in[7];
    const float* wo = (const float*)d_in[8];
    const float* bo = (const float*)d_in[9];
    const float* w1 = (const float*)d_in[10];
    const float* b1 = (const float*)d_in[11];
    const float* w2 = (const float*)d_in[12];
    const float* b2 = (const float*)d_in[13];
    const float* gamma1 = (const float*)d_in[14];
    const float* beta1 = (const float*)d_in[15];
    const float* gamma2 = (const float*)d_in[16];
    const float* beta2 = (const float*)d_in[17];

    char* ws = (char*)d_ws;
    bf16_t* wqkv = (bf16_t*)(ws + 0);
    bf16_t* wob = (bf16_t*)(ws + 6 * MB);
    bf16_t* w1b = (bf16_t*)(ws + 8 * MB);
    bf16_t* w2b = (bf16_t*)(ws + 16 * MB);
    bf16_t* xnb = (bf16_t*)(ws + 24 * MB);
    bf16_t* qb = (bf16_t*)(ws + 32 * MB);
    bf16_t* kb = (bf16_t*)(ws + 40 * MB);
    bf16_t* vtb = (bf16_t*)(ws + 48 * MB);
    bf16_t* ctxb = (bf16_t*)(ws + 56 * MB);
    float* x1 = (float*)(ws + 64 * MB);
    bf16_t* hb = (bf16_t*)(ws + 32 * MB);    // reuses q/k/vT/ctx (dead by FFN1)
    bf16_t* opart = (bf16_t*)(ws + 64 * MB); // attn partials (dead before OP writes x1)
    float2* mlbuf = (float2*)(ws + 0);       // in wqkv region (dead after QKV)
    bf16_t* p0 = (bf16_t*)(ws + 0);          // FFN2 partial z=0
    bf16_t* p1 = (bf16_t*)(ws + 24 * MB);    // FFN2 partial z=1 (xnb dead)

    cvt_all<<<12288, 256, 0, stream>>>(wq, wk, wv, wo, w1, w2, wqkv, wob, w1b, w2b);

    // LN1
    ln_kernel<<<1024, 256, 0, stream>>>(x, xnb, gamma1, beta1);
    // QKV fused GEMM (256x128 tile, N=3072)
    gemmBig<0><<<dim3(16, 24), 512, 0, stream>>>(xnb, wqkv, 1024, bq, bk, bv, qb, kb, vtb);
    // attention: KV-split across independent blocks + merge
    attn_split<<<1024, 256, 0, stream>>>(qb, kb, vtb, opart, mlbuf);
    attn_merge<<<2048, 256, 0, stream>>>(opart, mlbuf, ctxb);
    // out-proj + residual -> x1 (fp32)
    gemm128sq<0><<<dim3(32, 8), 256, 0, stream>>>(ctxb, wob, 1024, 1024, bo, x, x1, nullptr);
    // LN2
    ln_kernel<<<1024, 256, 0, stream>>>(x1, xnb, gamma2, beta2);
    // FFN1 + relu (256x128 tile, N=4096)
    gemmBig<1><<<dim3(16, 32), 512, 0, stream>>>(xnb, w1b, 1024, b1, nullptr, nullptr, hb,
                                                 nullptr, nullptr);
    // FFN2 K-split-2 -> bf16 partials, then combine with residual -> d_out
    gemm128sq<1><<<dim3(32, 8, 2), 256, 0, stream>>>(hb, w2b, 4096, 2048, nullptr, nullptr,
                                                     p0, p1);
    ffn2_combine<<<4096, 256, 0, stream>>>(p0, p1, x1, b2, (float*)d_out);
}

// Round 13
// 217.699 us; speedup vs baseline: 1.0297x; 1.0297x over previous
//
#include <hip/hip_runtime.h>

// ---------------------------------------------------------------------------
// EncoderBlock: pre-LN transformer block, B=2 S=2048 D=1024 H=16 dk=64 F=4096
// R13: consolidation of best-measured pieces. Attention = R8's single-kernel
//     (grid 512, XCD-swizzled, no split/merge) + R11's upgrades (gload_lds
//     2-slot ring w/ counted vmcnt(4), tree softmax, VGPR<=64, bounds(256,4)).
//     GEMMs = R8/R11 config (gemm256 4-slot lookahead-3; gemm128sq 4-slot;
//     FFN2 K-split-2 + combine). R12's gemmBig re-tile reverted (regressed).
// Workspace layout (80 MB used):
//   [0,6M)    wqkv bf16 (dead after QKV) -> p0 bf16 for FFN2
//   [6M,8M)   wo bf16
//   [8M,16M)  w1 bf16
//   [16M,24M) w2 bf16
//   [24M,32M) xn bf16 (LN out; dead after FFN1) -> p1 bf16 for FFN2
//   [32M,40M) q bf16 [B,H,S,64] (scaled by 0.125*log2e)  } reused as h for FFN1
//   [40M,48M) k bf16 [B,H,S,64]                          }
//   [48M,56M) vT bf16 [B,H,64,S]                         }
//   [56M,64M) ctx bf16 flat [B*S,1024]                   }
//   [64M,80M) x1 fp32 (residual after attention)
// ---------------------------------------------------------------------------

typedef __bf16 bf16_t;
typedef __attribute__((ext_vector_type(8))) __bf16 bf16x8;
typedef __attribute__((ext_vector_type(4))) __bf16 bf16x4;
typedef __attribute__((ext_vector_type(2))) __bf16 bf16x2;
typedef __attribute__((ext_vector_type(4))) float f32x4;
typedef __attribute__((ext_vector_type(16))) float f32x16;
typedef __attribute__((ext_vector_type(2))) unsigned uint32x2;
typedef __attribute__((ext_vector_type(4))) unsigned uint32x4;

#define MB (1024ull * 1024ull)
#define QSCALE 0.18033688011112043f /* 0.125 * log2(e) */

__device__ __forceinline__ void gload_lds16(const bf16_t* g, bf16_t* l) {
    __builtin_amdgcn_global_load_lds(
        (const __attribute__((address_space(1))) void*)g,
        (__attribute__((address_space(3))) void*)l, 16, 0, 0);
}

// Bank-slot XOR for BK=32 (64B) LDS rows: slot ^= (row>>1)&3 (2-way max).
__device__ __forceinline__ int bswz(int row) { return ((row >> 1) & 3) << 3; }

// XOR swizzle for 64-col bf16 LDS tiles (128B rows). (attn + v-transpose)
__device__ __forceinline__ int swz(int row, int col) {
    return row * 64 + ((((col >> 3) ^ row) & 7) << 3) + (col & 7);
}

__device__ __forceinline__ unsigned cvtpk(float a, float b) {
    bf16x2 v = {(__bf16)a, (__bf16)b};
    return __builtin_bit_cast(unsigned, v);
}

// --------------------------- fp32 -> bf16 convert (merged) ------------------
__global__ __launch_bounds__(256) void cvt_all(
    const float* __restrict__ wq, const float* __restrict__ wk,
    const float* __restrict__ wv, const float* __restrict__ wo,
    const float* __restrict__ w1, const float* __restrict__ w2,
    bf16_t* __restrict__ wqkv, bf16_t* __restrict__ wob, bf16_t* __restrict__ w1b,
    bf16_t* __restrict__ w2b) {
    const int b = blockIdx.x, t = threadIdx.x;
    const float* in;
    bf16_t* out;
    int i;
    if (b < 1024) { in = wq; out = wqkv; i = b * 256 + t; }
    else if (b < 2048) { in = wk; out = wqkv + 1048576; i = (b - 1024) * 256 + t; }
    else if (b < 3072) { in = wv; out = wqkv + 2097152; i = (b - 2048) * 256 + t; }
    else if (b < 4096) { in = wo; out = wob; i = (b - 3072) * 256 + t; }
    else if (b < 8192) { in = w1; out = w1b; i = (b - 4096) * 256 + t; }
    else { in = w2; out = w2b; i = (b - 8192) * 256 + t; }
    float4 v = ((const float4*)in)[i];
    bf16x4 o = {(__bf16)v.x, (__bf16)v.y, (__bf16)v.z, (__bf16)v.w};
    ((bf16x4*)out)[i] = o;
}

// --------------------------- LayerNorm (torch-style) ------------------------
__global__ __launch_bounds__(256) void ln_kernel(const float* __restrict__ x,
                                                 bf16_t* __restrict__ out,
                                                 const float* __restrict__ gamma,
                                                 const float* __restrict__ beta) {
    const int lane = threadIdx.x & 63;
    const int row = blockIdx.x * 4 + (threadIdx.x >> 6);
    const float* xr = x + (size_t)row * 1024;
    float4 v[4];
    float s = 0.f;
#pragma unroll
    for (int i = 0; i < 4; ++i) {
        v[i] = ((const float4*)xr)[i * 64 + lane];
        s += v[i].x + v[i].y + v[i].z + v[i].w;
    }
#pragma unroll
    for (int o = 32; o; o >>= 1) s += __shfl_xor(s, o);
    float mean = s * (1.f / 1024.f);
    float vs = 0.f;
#pragma unroll
    for (int i = 0; i < 4; ++i) {
        float a = v[i].x - mean, b = v[i].y - mean, c = v[i].z - mean, d = v[i].w - mean;
        vs += a * a + b * b + c * c + d * d;
    }
#pragma unroll
    for (int o = 32; o; o >>= 1) vs += __shfl_xor(vs, o);
    float inv = 1.f / (sqrtf(vs * (1.f / 1023.f)) + 1e-5f);
    float g = gamma[0] * inv, bb = beta[0];
    bf16_t* orow = out + (size_t)row * 1024;
#pragma unroll
    for (int i = 0; i < 4; ++i) {
        bf16x4 ov = {(__bf16)((v[i].x - mean) * g + bb), (__bf16)((v[i].y - mean) * g + bb),
                     (__bf16)((v[i].z - mean) * g + bb), (__bf16)((v[i].w - mean) * g + bb)};
        *(bf16x4*)(orow + (i * 64 + lane) * 4) = ov;
    }
}

// ------------------- Pipelined 256x256 GEMM (C = A @ W^T) -------------------
// 8 waves (2M x 4N), BK=32, 4-slot LDS ring, lookahead 3, counted vmcnt.
template <int KERN>
__global__ __launch_bounds__(512, 2) void gemm256(
    const bf16_t* __restrict__ A, const bf16_t* __restrict__ Bw, int K,
    const float* __restrict__ bias0, const float* __restrict__ bias1,
    const float* __restrict__ bias2, void* __restrict__ o0, void* __restrict__ o1,
    void* __restrict__ o2) {
    __shared__ bf16_t L[4 * 16384];  // 4 slots x (A 256x32 + B 256x32) = 128KB
    const int t = threadIdx.x, lane = t & 63, w = t >> 6;
    const int wm = w >> 2, wn = w & 3;
    const int l15 = lane & 15, l4 = lane >> 4;
    const int bm = blockIdx.x, bn = blockIdx.y;
    const int NT = K >> 5;
    const bf16_t* Ab = A + (size_t)bm * 256 * K;
    const bf16_t* Bb = Bw + (size_t)bn * 256 * K;
    const int srow = t >> 2, pcol = (t & 3) * 8;
    f32x4 acc[8][4] = {};

    auto stageA = [&](int tt) {
        bf16_t* s = L + (tt & 3) * 16384;
        const int kb = tt * 32;
#pragma unroll
        for (int i = 0; i < 2; ++i) {
            int row = i * 128 + srow;
            int lcol = pcol ^ bswz(row);
            gload_lds16(Ab + (size_t)row * K + kb + lcol, s + i * 4096 + t * 8);
        }
    };
    auto stageB = [&](int tt) {
        bf16_t* s = L + (tt & 3) * 16384 + 8192;
        const int kb = tt * 32;
#pragma unroll
        for (int i = 0; i < 2; ++i) {
            int row = i * 128 + srow;
            int lcol = pcol ^ bswz(row);
            gload_lds16(Bb + (size_t)row * K + kb + lcol, s + i * 4096 + t * 8);
        }
    };

    stageA(0); stageB(0); stageA(1); stageB(1); stageA(2); stageB(2);
    asm volatile("s_waitcnt vmcnt(8)" ::: "memory");
    __builtin_amdgcn_s_barrier();

    for (int tt = 0; tt < NT; ++tt) {
        bf16_t* s = L + (tt & 3) * 16384;
        bf16_t* sB = s + 8192;
        bf16x8 af[4], bfr[4];
#pragma unroll
        for (int m = 0; m < 4; ++m) {
            int row = wm * 128 + m * 16 + l15;
            af[m] = *(const bf16x8*)(s + row * 32 + ((l4 * 8) ^ bswz(row)));
        }
#pragma unroll
        for (int n = 0; n < 4; ++n) {
            int row = wn * 64 + n * 16 + l15;
            bfr[n] = *(const bf16x8*)(sB + row * 32 + ((l4 * 8) ^ bswz(row)));
        }
        if (tt + 3 < NT) stageA(tt + 3);
        __builtin_amdgcn_s_barrier();
        __builtin_amdgcn_s_setprio(1);
#pragma unroll
        for (int m = 0; m < 4; ++m)
#pragma unroll
            for (int n = 0; n < 4; ++n)
                acc[m][n] = __builtin_amdgcn_mfma_f32_16x16x32_bf16(af[m], bfr[n], acc[m][n],
                                                                   0, 0, 0);
        __builtin_amdgcn_s_setprio(0);
        __builtin_amdgcn_s_barrier();
#pragma unroll
        for (int m = 0; m < 4; ++m) {
            int row = wm * 128 + 64 + m * 16 + l15;
            af[m] = *(const bf16x8*)(s + row * 32 + ((l4 * 8) ^ bswz(row)));
        }
        if (tt + 3 < NT) stageB(tt + 3);
        __builtin_amdgcn_s_barrier();
        __builtin_amdgcn_s_setprio(1);
#pragma unroll
        for (int m = 0; m < 4; ++m)
#pragma unroll
            for (int n = 0; n < 4; ++n)
                acc[4 + m][n] = __builtin_amdgcn_mfma_f32_16x16x32_bf16(af[m], bfr[n],
                                                                       acc[4 + m][n], 0, 0, 0);
        __builtin_amdgcn_s_setprio(0);
        if (tt + 3 < NT)
            asm volatile("s_waitcnt vmcnt(8)" ::: "memory");
        else if (tt + 2 < NT)
            asm volatile("s_waitcnt vmcnt(4)" ::: "memory");
        else
            asm volatile("s_waitcnt vmcnt(0)" ::: "memory");
        __builtin_amdgcn_s_barrier();
    }

    if (KERN == 1) {
        const int colb = bn * 256 + wn * 64;
        float bb[4];
#pragma unroll
        for (int n = 0; n < 4; ++n) bb[n] = bias0[colb + n * 16 + l15];
#pragma unroll
        for (int m = 0; m < 8; ++m) {
            const int row0 = bm * 256 + wm * 128 + m * 16 + (l4 << 2);
#pragma unroll
            for (int n = 0; n < 4; ++n)
#pragma unroll
                for (int j = 0; j < 4; ++j) {
                    float v = acc[m][n][j] + bb[n];
                    ((bf16_t*)o0)[(size_t)(row0 + j) * 4096 + colb + n * 16 + l15] =
                        (bf16_t)(v > 0.f ? v : 0.f);
                }
        }
        return;
    }
    // KERN 0: QKV
    if (bn < 8) {
        const bool isq = bn < 4;
        const float* bias = isq ? bias0 : bias1;
        const int head = (bn & 3) * 4 + wn;
        const int b = (bm * 256) >> 11;
        const int srow0 = (bm * 256 + wm * 128) & 2047;
        bf16_t* dst = (bf16_t*)(isq ? o0 : o1) + ((size_t)(b * 16 + head) << 17);
        float bb[4];
#pragma unroll
        for (int n = 0; n < 4; ++n) bb[n] = bias[head * 64 + n * 16 + l15];
#pragma unroll
        for (int m = 0; m < 8; ++m)
#pragma unroll
            for (int n = 0; n < 4; ++n)
#pragma unroll
                for (int j = 0; j < 4; ++j) {
                    int srw = srow0 + m * 16 + (l4 << 2) + j;
                    float v = acc[m][n][j] + bb[n];
                    if (isq) v *= QSCALE;
                    dst[((size_t)srw << 6) + n * 16 + l15] = (bf16_t)v;
                }
    } else {
        // v: per-wave LDS transpose -> [B,H,64,S] coalesced
        const int head = (bn - 8) * 4 + wn;
        const int b = (bm * 256) >> 11;
        const int sbase = (bm * 256 + wm * 128) & 2047;
        bf16_t* P = L + w * 8192;
        float bb[4];
#pragma unroll
        for (int n = 0; n < 4; ++n) bb[n] = bias2[head * 64 + n * 16 + l15];
#pragma unroll
        for (int m = 0; m < 8; ++m)
#pragma unroll
            for (int n = 0; n < 4; ++n) {
                int d = n * 16 + l15;
                int sl = m * 16 + (l4 << 2);
                bf16x4 pk = {(__bf16)(acc[m][n][0] + bb[n]), (__bf16)(acc[m][n][1] + bb[n]),
                             (__bf16)(acc[m][n][2] + bb[n]), (__bf16)(acc[m][n][3] + bb[n])};
                *(bf16x4*)(P + d * 128 + (sl ^ ((d & 7) << 3))) = pk;
            }
#pragma unroll
        for (int p = 0; p < 16; ++p) {
            int id = p * 64 + lane;
            int d = id >> 4, c8 = (id & 15) * 8;
            bf16x8 vv = *(const bf16x8*)(P + d * 128 + (c8 ^ ((d & 7) << 3)));
            *(bf16x8*)((bf16_t*)o2 + (((size_t)(b * 16 + head) * 64 + d) << 11) + sbase + c8) =
                vv;
        }
    }
}

// ------------- Pipelined 128x128 GEMM, wave=64x64 (C = A @ W^T) -------------
// 4-slot ring, lookahead 3, counted vmcnt. SPLIT=0: +bias +resid -> fp32.
// SPLIT=1: K-split via blockIdx.z, raw partial -> bf16.
template <int SPLIT>
__global__ __launch_bounds__(256, 2) void gemm128sq(
    const bf16_t* __restrict__ A, const bf16_t* __restrict__ Bw, int stride, int Ks,
    const float* __restrict__ bias, const float* __restrict__ resid,
    void* __restrict__ o0, void* __restrict__ o1) {
    __shared__ bf16_t L[4 * 8192];  // 4 slots x (A 128x32 + B 128x32) = 64KB
    const int t = threadIdx.x, lane = t & 63, w = t >> 6;
    const int wr = w >> 1, wc = w & 1;
    const int l15 = lane & 15, l4 = lane >> 4;
    const int bm = blockIdx.x, bn = blockIdx.y;
    const int NT = Ks >> 5;
    const size_t kofs = SPLIT ? (size_t)blockIdx.z * Ks : 0;
    const bf16_t* Ab = A + (size_t)bm * 128 * stride + kofs;
    const bf16_t* Bb = Bw + (size_t)bn * 128 * stride + kofs;
    const int srow = t >> 2, pcol = (t & 3) * 8;
    f32x4 acc[4][4] = {};

    auto STAGE = [&](int tt) {
        bf16_t* s = L + (tt & 3) * 8192;
        const int kb = tt * 32;
#pragma unroll
        for (int i = 0; i < 2; ++i) {
            int row = i * 64 + srow;
            int lcol = pcol ^ bswz(row);
            gload_lds16(Ab + (size_t)row * stride + kb + lcol, s + i * 2048 + t * 8);
            gload_lds16(Bb + (size_t)row * stride + kb + lcol, s + 4096 + i * 2048 + t * 8);
        }
    };

    STAGE(0); STAGE(1); STAGE(2);
    asm volatile("s_waitcnt vmcnt(8)" ::: "memory");
    __builtin_amdgcn_s_barrier();

    for (int tt = 0; tt < NT; ++tt) {
        bf16_t* s = L + (tt & 3) * 8192;
        bf16x8 af[4], bfr[4];
#pragma unroll
        for (int m = 0; m < 4; ++m) {
            int row = wr * 64 + m * 16 + l15;
            af[m] = *(const bf16x8*)(s + row * 32 + ((l4 * 8) ^ bswz(row)));
        }
#pragma unroll
        for (int n = 0; n < 4; ++n) {
            int row = wc * 64 + n * 16 + l15;
            bfr[n] = *(const bf16x8*)(s + 4096 + row * 32 + ((l4 * 8) ^ bswz(row)));
        }
        if (tt + 3 < NT) STAGE(tt + 3);
        __builtin_amdgcn_s_barrier();
        __builtin_amdgcn_s_setprio(1);
#pragma unroll
        for (int m = 0; m < 4; ++m)
#pragma unroll
            for (int n = 0; n < 4; ++n)
                acc[m][n] = __builtin_amdgcn_mfma_f32_16x16x32_bf16(af[m], bfr[n], acc[m][n],
                                                                   0, 0, 0);
        __builtin_amdgcn_s_setprio(0);
        if (tt + 3 < NT)
            asm volatile("s_waitcnt vmcnt(8)" ::: "memory");
        else if (tt + 2 < NT)
            asm volatile("s_waitcnt vmcnt(4)" ::: "memory");
        else
            asm volatile("s_waitcnt vmcnt(0)" ::: "memory");
        __builtin_amdgcn_s_barrier();
    }

#pragma unroll
    for (int m = 0; m < 4; ++m) {
        const int row0 = bm * 128 + wr * 64 + m * 16 + (l4 << 2);
#pragma unroll
        for (int n = 0; n < 4; ++n) {
            const int col = bn * 128 + wc * 64 + n * 16 + l15;
#pragma unroll
            for (int j = 0; j < 4; ++j) {
                const int row = row0 + j;
                if (SPLIT == 0) {
                    ((float*)o0)[(size_t)row * 1024 + col] =
                        resid[(size_t)row * 1024 + col] + acc[m][n][j] + bias[col];
                } else {
                    bf16_t* po = (bf16_t*)(blockIdx.z ? o1 : o0);
                    po[(size_t)row * 1024 + col] = (bf16_t)acc[m][n][j];
                }
            }
        }
    }
}

// ---- FFN2 combine: out = p0 + p1 + resid + bias (fp32), 4096x1024 ----------
__global__ __launch_bounds__(256) void ffn2_combine(
    const bf16_t* __restrict__ p0, const bf16_t* __restrict__ p1,
    const float* __restrict__ resid, const float* __restrict__ bias,
    float* __restrict__ out) {
    int i = blockIdx.x * 256 + threadIdx.x;  // float4 index, 1M total
    float4 r = ((const float4*)resid)[i];
    bf16x4 a = ((const bf16x4*)p0)[i];
    bf16x4 b = ((const bf16x4*)p1)[i];
    float4 bs = ((const float4*)bias)[i & 255];
    float4 o;
    o.x = r.x + (float)a.x + (float)b.x + bs.x;
    o.y = r.y + (float)a.y + (float)b.y + bs.y;
    o.z = r.z + (float)a.z + (float)b.z + bs.z;
    o.w = r.w + (float)a.w + (float)b.w + bs.w;
    ((float4*)out)[i] = o;
}

// --------------------------- Flash attention (R13) --------------------------
// Single kernel, grid 512, XCD-swizzled (all 16 q-tiles of a head on one XCD).
// 4 waves x 32 q-rows, full 2048 keys. K/V staged via global_load_lds 2-slot
// ring w/ counted vmcnt(4) (linear dest, inverse-swizzled source, swz reads).
// 32x32x16 MFMA, swapped QK^T+PV, lane-local tree softmax, P in registers.
__global__ __launch_bounds__(256, 4) void attn_kernel(const bf16_t* __restrict__ q,
                                                      const bf16_t* __restrict__ k,
                                                      const bf16_t* __restrict__ vt,
                                                      bf16_t* __restrict__ ctx) {
    __shared__ bf16_t Kl[2][64 * 64];
    __shared__ bf16_t Vl[2][64 * 64];
    const int t = threadIdx.x, lane = t & 63, w = t >> 6;
    const int bid = blockIdx.x;
    const int xcd = bid & 7, j = bid >> 3;
    const int bh = xcd + ((j >> 4) << 3);
    const int qx = j & 15;
    const bf16_t* qg = q + (size_t)bh * 2048 * 64;
    const bf16_t* kg = k + (size_t)bh * 2048 * 64;
    const bf16_t* vg = vt + (size_t)bh * 64 * 2048;
    const int l31 = lane & 31, h = lane >> 5;
    const int rowl = w * 32 + l31;
    const int qrow = qx * 128 + rowl;
    // staging geometry: thread t owns phys chunk p of rows prow / prow+32;
    // linear dest t*16B holds source chunk (p ^ prow)&7 (swz inverse)
    const int prow = t >> 3, p = t & 7;
    const int sc = ((p ^ prow) & 7) * 8;

    bf16x8 qf[4];
#pragma unroll
    for (int kd = 0; kd < 4; ++kd)
        qf[kd] = *(const bf16x8*)(qg + (size_t)qrow * 64 + kd * 16 + h * 8);

    f32x16 o0 = {}, o1 = {};
    float mi = -1e30f, li = 0.f;

    auto STAGE = [&](int tt) {
        bf16_t* kd_ = Kl[tt & 1];
        bf16_t* vd_ = Vl[tt & 1];
        const int kb = tt * 64;
        gload_lds16(kg + (size_t)(kb + prow) * 64 + sc, kd_ + t * 8);
        gload_lds16(kg + (size_t)(kb + prow + 32) * 64 + sc, kd_ + 2048 + t * 8);
        gload_lds16(vg + (size_t)prow * 2048 + kb + sc, vd_ + t * 8);
        gload_lds16(vg + (size_t)(prow + 32) * 2048 + kb + sc, vd_ + 2048 + t * 8);
    };

    STAGE(0);
    const int NT = 32;
    for (int tt = 0; tt < NT; ++tt) {
        if (tt + 1 < NT) {
            STAGE(tt + 1);
            asm volatile("s_waitcnt vmcnt(4)" ::: "memory");
        } else {
            asm volatile("s_waitcnt vmcnt(0)" ::: "memory");
        }
        __builtin_amdgcn_s_barrier();
        const bf16_t* Kb = Kl[tt & 1];
        const bf16_t* Vb = Vl[tt & 1];
        f32x16 sT0 = {}, sT1 = {};
        __builtin_amdgcn_s_setprio(1);
#pragma unroll
        for (int kd = 0; kd < 4; ++kd) {
            bf16x8 ka0 = *(const bf16x8*)(Kb + swz(l31, kd * 16 + h * 8));
            bf16x8 ka1 = *(const bf16x8*)(Kb + swz(32 + l31, kd * 16 + h * 8));
            sT0 = __builtin_amdgcn_mfma_f32_32x32x16_bf16(ka0, qf[kd], sT0, 0, 0, 0);
            sT1 = __builtin_amdgcn_mfma_f32_32x32x16_bf16(ka1, qf[kd], sT1, 0, 0, 0);
        }
        __builtin_amdgcn_s_setprio(0);
        // tree-reduced row max (depth 5)
        float pm[16];
#pragma unroll
        for (int i = 0; i < 16; ++i) pm[i] = fmaxf(sT0[i], sT1[i]);
#pragma unroll
        for (int st = 8; st; st >>= 1)
#pragma unroll
            for (int i = 0; i < st; ++i) pm[i] = fmaxf(pm[i], pm[i + st]);
        float mx = fmaxf(pm[0], __shfl_xor(pm[0], 32));
        if (!__all(mx <= mi + 8.f)) {
            float mn = fmaxf(mi, mx);
            float al = __builtin_amdgcn_exp2f(mi - mn);
            mi = mn;
            li *= al;
            o0 *= al;
            o1 *= al;
        }
        f32x16 e0, e1;
#pragma unroll
        for (int i = 0; i < 16; ++i) e0[i] = __builtin_amdgcn_exp2f(sT0[i] - mi);
#pragma unroll
        for (int i = 0; i < 16; ++i) e1[i] = __builtin_amdgcn_exp2f(sT1[i] - mi);
        // tree-reduced row sum (depth 5)
        float ps[16];
#pragma unroll
        for (int i = 0; i < 16; ++i) ps[i] = e0[i] + e1[i];
#pragma unroll
        for (int st = 8; st; st >>= 1)
#pragma unroll
            for (int i = 0; i < st; ++i) ps[i] += ps[i + st];
        li += ps[0] + __shfl_xor(ps[0], 32);
        bf16x8 pa[4];
#pragma unroll
        for (int kd = 0; kd < 4; ++kd) {
            const f32x16& e = (kd < 2) ? e0 : e1;
            const int R0l = 8 * (kd & 1);
            const int R0h = R0l + 4;
            unsigned U0 = cvtpk(e[R0l + 0], e[R0l + 1]);
            unsigned V0 = cvtpk(e[R0l + 2], e[R0l + 3]);
            unsigned U1 = cvtpk(e[R0h + 0], e[R0h + 1]);
            unsigned V1 = cvtpk(e[R0h + 2], e[R0h + 3]);
            uint32x2 ru = __builtin_amdgcn_permlane32_swap(U0, U1, false, false);
            uint32x2 rv = __builtin_amdgcn_permlane32_swap(V0, V1, false, false);
            uint32x4 pw = {ru.x, rv.x, ru.y, rv.y};
            pa[kd] = __builtin_bit_cast(bf16x8, pw);
        }
        __builtin_amdgcn_s_setprio(1);
#pragma unroll
        for (int kd = 0; kd < 4; ++kd) {
            bf16x8 va0 = *(const bf16x8*)(Vb + swz(l31, kd * 16 + h * 8));
            bf16x8 va1 = *(const bf16x8*)(Vb + swz(32 + l31, kd * 16 + h * 8));
            o0 = __builtin_amdgcn_mfma_f32_32x32x16_bf16(va0, pa[kd], o0, 0, 0, 0);
            o1 = __builtin_amdgcn_mfma_f32_32x32x16_bf16(va1, pa[kd], o1, 0, 0, 0);
        }
        __builtin_amdgcn_s_setprio(0);
        __builtin_amdgcn_s_barrier();  // all waves done with slot tt&1 before re-stage
    }
    // epilogue: direct ctx write (lane-local 1/l)
    float inv = 1.f / li;
    size_t base = ((size_t)(bh >> 4) * 2048 + qrow) * 1024 + (bh & 15) * 64;
#pragma unroll
    for (int g = 0; g < 4; ++g) {
        bf16x4 ov0 = {(__bf16)(o0[4 * g + 0] * inv), (__bf16)(o0[4 * g + 1] * inv),
                      (__bf16)(o0[4 * g + 2] * inv), (__bf16)(o0[4 * g + 3] * inv)};
        *(bf16x4*)(ctx + base + 8 * g + 4 * h) = ov0;
        bf16x4 ov1 = {(__bf16)(o1[4 * g + 0] * inv), (__bf16)(o1[4 * g + 1] * inv),
                      (__bf16)(o1[4 * g + 2] * inv), (__bf16)(o1[4 * g + 3] * inv)};
        *(bf16x4*)(ctx + base + 32 + 8 * g + 4 * h) = ov1;
    }
}

// ---------------------------------------------------------------------------
extern "C" void kernel_launch(void* const* d_in, const int* in_sizes, int n_in,
                              void* d_out, int out_size, void* d_ws, size_t ws_size,
                              hipStream_t stream) {
    const float* x = (const float*)d_in[0];
    const float* wq = (const float*)d_in[2];
    const float* bq = (const float*)d_in[3];
    const float* wk = (const float*)d_in[4];
    const float* bk = (const float*)d_in[5];
    const float* wv = (const float*)d_in[6];
    const float* bv = (const float*)d_in[7];
    const float* wo = (const float*)d_in[8];
    const float* bo = (const float*)d_in[9];
    const float* w1 = (const float*)d_in[10];
    const float* b1 = (const float*)d_in[11];
    const float* w2 = (const float*)d_in[12];
    const float* b2 = (const float*)d_in[13];
    const float* gamma1 = (const float*)d_in[14];
    const float* beta1 = (const float*)d_in[15];
    const float* gamma2 = (const float*)d_in[16];
    const float* beta2 = (const float*)d_in[17];

    char* ws = (char*)d_ws;
    bf16_t* wqkv = (bf16_t*)(ws + 0);
    bf16_t* wob = (bf16_t*)(ws + 6 * MB);
    bf16_t* w1b = (bf16_t*)(ws + 8 * MB);
    bf16_t* w2b = (bf16_t*)(ws + 16 * MB);
    bf16_t* xnb = (bf16_t*)(ws + 24 * MB);
    bf16_t* qb = (bf16_t*)(ws + 32 * MB);
    bf16_t* kb = (bf16_t*)(ws + 40 * MB);
    bf16_t* vtb = (bf16_t*)(ws + 48 * MB);
    bf16_t* ctxb = (bf16_t*)(ws + 56 * MB);
    float* x1 = (float*)(ws + 64 * MB);
    bf16_t* hb = (bf16_t*)(ws + 32 * MB);  // reuses q/k/vT/ctx (dead by FFN1)
    bf16_t* p0 = (bf16_t*)(ws + 0);        // FFN2 partial z=0 (wqkv/wob dead)
    bf16_t* p1 = (bf16_t*)(ws + 24 * MB);  // FFN2 partial z=1 (xnb dead)

    cvt_all<<<12288, 256, 0, stream>>>(wq, wk, wv, wo, w1, w2, wqkv, wob, w1b, w2b);

    // LN1
    ln_kernel<<<1024, 256, 0, stream>>>(x, xnb, gamma1, beta1);
    // QKV fused GEMM (256x256, N=3072)
    gemm256<0><<<dim3(16, 12), 512, 0, stream>>>(xnb, wqkv, 1024, bq, bk, bv, qb, kb, vtb);
    // attention (single kernel, XCD-swizzled)
    attn_kernel<<<512, 256, 0, stream>>>(qb, kb, vtb, ctxb);
    // out-proj + residual -> x1 (fp32)
    gemm128sq<0><<<dim3(32, 8), 256, 0, stream>>>(ctxb, wob, 1024, 1024, bo, x, x1, nullptr);
    // LN2
    ln_kernel<<<1024, 256, 0, stream>>>(x1, xnb, gamma2, beta2);
    // FFN1 + relu (256x256, N=4096)
    gemm256<1><<<dim3(16, 16), 512, 0, stream>>>(xnb, w1b, 1024, b1, nullptr, nullptr, hb,
                                                 nullptr, nullptr);
    // FFN2 K-split-2 -> bf16 partials, then combine with residual -> d_out
    gemm128sq<1><<<dim3(32, 8, 2), 256, 0, stream>>>(hb, w2b, 4096, 2048, nullptr, nullptr,
                                                     p0, p1);
    ffn2_combine<<<4096, 256, 0, stream>>>(p0, p1, x1, b2, (float*)d_out);
}

// Round 14
// 213.161 us; speedup vs baseline: 1.0517x; 1.0213x over previous
//
#include <hip/hip_runtime.h>

// ---------------------------------------------------------------------------
// EncoderBlock: pre-LN transformer block, B=2 S=2048 D=1024 H=16 dk=64 F=4096
// R14: attention = R8's reg-staged single-kernel core with KVBLK 64->128:
//     halves barrier count + serial softmax chains (32->16 iters), doubles
//     MFMA burst length. exp2 in-place into sT (VGPR control), single-buffer
//     LDS (K 128x64 swz, V 64x128 swzV), reg prefetch of next tile.
//     GEMMs unchanged from R13 (gemm256 4-slot; gemm128sq 4-slot; FFN2 split).
// Workspace layout (80 MB used):
//   [0,6M)    wqkv bf16 (dead after QKV) -> p0 bf16 for FFN2
//   [6M,8M)   wo bf16
//   [8M,16M)  w1 bf16
//   [16M,24M) w2 bf16
//   [24M,32M) xn bf16 (LN out; dead after FFN1) -> p1 bf16 for FFN2
//   [32M,40M) q bf16 [B,H,S,64] (scaled by 0.125*log2e)  } reused as h for FFN1
//   [40M,48M) k bf16 [B,H,S,64]                          }
//   [48M,56M) vT bf16 [B,H,64,S]                         }
//   [56M,64M) ctx bf16 flat [B*S,1024]                   }
//   [64M,80M) x1 fp32 (residual after attention)
// ---------------------------------------------------------------------------

typedef __bf16 bf16_t;
typedef __attribute__((ext_vector_type(8))) __bf16 bf16x8;
typedef __attribute__((ext_vector_type(4))) __bf16 bf16x4;
typedef __attribute__((ext_vector_type(2))) __bf16 bf16x2;
typedef __attribute__((ext_vector_type(4))) float f32x4;
typedef __attribute__((ext_vector_type(16))) float f32x16;
typedef __attribute__((ext_vector_type(2))) unsigned uint32x2;
typedef __attribute__((ext_vector_type(4))) unsigned uint32x4;

#define MB (1024ull * 1024ull)
#define QSCALE 0.18033688011112043f /* 0.125 * log2(e) */

__device__ __forceinline__ void gload_lds16(const bf16_t* g, bf16_t* l) {
    __builtin_amdgcn_global_load_lds(
        (const __attribute__((address_space(1))) void*)g,
        (__attribute__((address_space(3))) void*)l, 16, 0, 0);
}

// Bank-slot XOR for BK=32 (64B) LDS rows: slot ^= (row>>1)&3 (2-way max).
__device__ __forceinline__ int bswz(int row) { return ((row >> 1) & 3) << 3; }

// XOR swizzle for 64-col bf16 LDS tiles (128B rows, 8 chunks).
__device__ __forceinline__ int swz(int row, int col) {
    return row * 64 + ((((col >> 3) ^ row) & 7) << 3) + (col & 7);
}

// XOR swizzle for 128-col bf16 LDS tiles (256B rows, 16 chunks). (attn V)
__device__ __forceinline__ int swzV(int row, int col) {
    return row * 128 + ((((col >> 3) ^ row) & 15) << 3) + (col & 7);
}

__device__ __forceinline__ unsigned cvtpk(float a, float b) {
    bf16x2 v = {(__bf16)a, (__bf16)b};
    return __builtin_bit_cast(unsigned, v);
}

// --------------------------- fp32 -> bf16 convert (merged) ------------------
__global__ __launch_bounds__(256) void cvt_all(
    const float* __restrict__ wq, const float* __restrict__ wk,
    const float* __restrict__ wv, const float* __restrict__ wo,
    const float* __restrict__ w1, const float* __restrict__ w2,
    bf16_t* __restrict__ wqkv, bf16_t* __restrict__ wob, bf16_t* __restrict__ w1b,
    bf16_t* __restrict__ w2b) {
    const int b = blockIdx.x, t = threadIdx.x;
    const float* in;
    bf16_t* out;
    int i;
    if (b < 1024) { in = wq; out = wqkv; i = b * 256 + t; }
    else if (b < 2048) { in = wk; out = wqkv + 1048576; i = (b - 1024) * 256 + t; }
    else if (b < 3072) { in = wv; out = wqkv + 2097152; i = (b - 2048) * 256 + t; }
    else if (b < 4096) { in = wo; out = wob; i = (b - 3072) * 256 + t; }
    else if (b < 8192) { in = w1; out = w1b; i = (b - 4096) * 256 + t; }
    else { in = w2; out = w2b; i = (b - 8192) * 256 + t; }
    float4 v = ((const float4*)in)[i];
    bf16x4 o = {(__bf16)v.x, (__bf16)v.y, (__bf16)v.z, (__bf16)v.w};
    ((bf16x4*)out)[i] = o;
}

// --------------------------- LayerNorm (torch-style) ------------------------
__global__ __launch_bounds__(256) void ln_kernel(const float* __restrict__ x,
                                                 bf16_t* __restrict__ out,
                                                 const float* __restrict__ gamma,
                                                 const float* __restrict__ beta) {
    const int lane = threadIdx.x & 63;
    const int row = blockIdx.x * 4 + (threadIdx.x >> 6);
    const float* xr = x + (size_t)row * 1024;
    float4 v[4];
    float s = 0.f;
#pragma unroll
    for (int i = 0; i < 4; ++i) {
        v[i] = ((const float4*)xr)[i * 64 + lane];
        s += v[i].x + v[i].y + v[i].z + v[i].w;
    }
#pragma unroll
    for (int o = 32; o; o >>= 1) s += __shfl_xor(s, o);
    float mean = s * (1.f / 1024.f);
    float vs = 0.f;
#pragma unroll
    for (int i = 0; i < 4; ++i) {
        float a = v[i].x - mean, b = v[i].y - mean, c = v[i].z - mean, d = v[i].w - mean;
        vs += a * a + b * b + c * c + d * d;
    }
#pragma unroll
    for (int o = 32; o; o >>= 1) vs += __shfl_xor(vs, o);
    float inv = 1.f / (sqrtf(vs * (1.f / 1023.f)) + 1e-5f);
    float g = gamma[0] * inv, bb = beta[0];
    bf16_t* orow = out + (size_t)row * 1024;
#pragma unroll
    for (int i = 0; i < 4; ++i) {
        bf16x4 ov = {(__bf16)((v[i].x - mean) * g + bb), (__bf16)((v[i].y - mean) * g + bb),
                     (__bf16)((v[i].z - mean) * g + bb), (__bf16)((v[i].w - mean) * g + bb)};
        *(bf16x4*)(orow + (i * 64 + lane) * 4) = ov;
    }
}

// ------------------- Pipelined 256x256 GEMM (C = A @ W^T) -------------------
// 8 waves (2M x 4N), BK=32, 4-slot LDS ring, lookahead 3, counted vmcnt.
template <int KERN>
__global__ __launch_bounds__(512, 2) void gemm256(
    const bf16_t* __restrict__ A, const bf16_t* __restrict__ Bw, int K,
    const float* __restrict__ bias0, const float* __restrict__ bias1,
    const float* __restrict__ bias2, void* __restrict__ o0, void* __restrict__ o1,
    void* __restrict__ o2) {
    __shared__ bf16_t L[4 * 16384];  // 4 slots x (A 256x32 + B 256x32) = 128KB
    const int t = threadIdx.x, lane = t & 63, w = t >> 6;
    const int wm = w >> 2, wn = w & 3;
    const int l15 = lane & 15, l4 = lane >> 4;
    const int bm = blockIdx.x, bn = blockIdx.y;
    const int NT = K >> 5;
    const bf16_t* Ab = A + (size_t)bm * 256 * K;
    const bf16_t* Bb = Bw + (size_t)bn * 256 * K;
    const int srow = t >> 2, pcol = (t & 3) * 8;
    f32x4 acc[8][4] = {};

    auto stageA = [&](int tt) {
        bf16_t* s = L + (tt & 3) * 16384;
        const int kb = tt * 32;
#pragma unroll
        for (int i = 0; i < 2; ++i) {
            int row = i * 128 + srow;
            int lcol = pcol ^ bswz(row);
            gload_lds16(Ab + (size_t)row * K + kb + lcol, s + i * 4096 + t * 8);
        }
    };
    auto stageB = [&](int tt) {
        bf16_t* s = L + (tt & 3) * 16384 + 8192;
        const int kb = tt * 32;
#pragma unroll
        for (int i = 0; i < 2; ++i) {
            int row = i * 128 + srow;
            int lcol = pcol ^ bswz(row);
            gload_lds16(Bb + (size_t)row * K + kb + lcol, s + i * 4096 + t * 8);
        }
    };

    stageA(0); stageB(0); stageA(1); stageB(1); stageA(2); stageB(2);
    asm volatile("s_waitcnt vmcnt(8)" ::: "memory");
    __builtin_amdgcn_s_barrier();

    for (int tt = 0; tt < NT; ++tt) {
        bf16_t* s = L + (tt & 3) * 16384;
        bf16_t* sB = s + 8192;
        bf16x8 af[4], bfr[4];
#pragma unroll
        for (int m = 0; m < 4; ++m) {
            int row = wm * 128 + m * 16 + l15;
            af[m] = *(const bf16x8*)(s + row * 32 + ((l4 * 8) ^ bswz(row)));
        }
#pragma unroll
        for (int n = 0; n < 4; ++n) {
            int row = wn * 64 + n * 16 + l15;
            bfr[n] = *(const bf16x8*)(sB + row * 32 + ((l4 * 8) ^ bswz(row)));
        }
        if (tt + 3 < NT) stageA(tt + 3);
        __builtin_amdgcn_s_barrier();
        __builtin_amdgcn_s_setprio(1);
#pragma unroll
        for (int m = 0; m < 4; ++m)
#pragma unroll
            for (int n = 0; n < 4; ++n)
                acc[m][n] = __builtin_amdgcn_mfma_f32_16x16x32_bf16(af[m], bfr[n], acc[m][n],
                                                                   0, 0, 0);
        __builtin_amdgcn_s_setprio(0);
        __builtin_amdgcn_s_barrier();
#pragma unroll
        for (int m = 0; m < 4; ++m) {
            int row = wm * 128 + 64 + m * 16 + l15;
            af[m] = *(const bf16x8*)(s + row * 32 + ((l4 * 8) ^ bswz(row)));
        }
        if (tt + 3 < NT) stageB(tt + 3);
        __builtin_amdgcn_s_barrier();
        __builtin_amdgcn_s_setprio(1);
#pragma unroll
        for (int m = 0; m < 4; ++m)
#pragma unroll
            for (int n = 0; n < 4; ++n)
                acc[4 + m][n] = __builtin_amdgcn_mfma_f32_16x16x32_bf16(af[m], bfr[n],
                                                                       acc[4 + m][n], 0, 0, 0);
        __builtin_amdgcn_s_setprio(0);
        if (tt + 3 < NT)
            asm volatile("s_waitcnt vmcnt(8)" ::: "memory");
        else if (tt + 2 < NT)
            asm volatile("s_waitcnt vmcnt(4)" ::: "memory");
        else
            asm volatile("s_waitcnt vmcnt(0)" ::: "memory");
        __builtin_amdgcn_s_barrier();
    }

    if (KERN == 1) {
        const int colb = bn * 256 + wn * 64;
        float bb[4];
#pragma unroll
        for (int n = 0; n < 4; ++n) bb[n] = bias0[colb + n * 16 + l15];
#pragma unroll
        for (int m = 0; m < 8; ++m) {
            const int row0 = bm * 256 + wm * 128 + m * 16 + (l4 << 2);
#pragma unroll
            for (int n = 0; n < 4; ++n)
#pragma unroll
                for (int j = 0; j < 4; ++j) {
                    float v = acc[m][n][j] + bb[n];
                    ((bf16_t*)o0)[(size_t)(row0 + j) * 4096 + colb + n * 16 + l15] =
                        (bf16_t)(v > 0.f ? v : 0.f);
                }
        }
        return;
    }
    // KERN 0: QKV
    if (bn < 8) {
        const bool isq = bn < 4;
        const float* bias = isq ? bias0 : bias1;
        const int head = (bn & 3) * 4 + wn;
        const int b = (bm * 256) >> 11;
        const int srow0 = (bm * 256 + wm * 128) & 2047;
        bf16_t* dst = (bf16_t*)(isq ? o0 : o1) + ((size_t)(b * 16 + head) << 17);
        float bb[4];
#pragma unroll
        for (int n = 0; n < 4; ++n) bb[n] = bias[head * 64 + n * 16 + l15];
#pragma unroll
        for (int m = 0; m < 8; ++m)
#pragma unroll
            for (int n = 0; n < 4; ++n)
#pragma unroll
                for (int j = 0; j < 4; ++j) {
                    int srw = srow0 + m * 16 + (l4 << 2) + j;
                    float v = acc[m][n][j] + bb[n];
                    if (isq) v *= QSCALE;
                    dst[((size_t)srw << 6) + n * 16 + l15] = (bf16_t)v;
                }
    } else {
        // v: per-wave LDS transpose -> [B,H,64,S] coalesced
        const int head = (bn - 8) * 4 + wn;
        const int b = (bm * 256) >> 11;
        const int sbase = (bm * 256 + wm * 128) & 2047;
        bf16_t* P = L + w * 8192;
        float bb[4];
#pragma unroll
        for (int n = 0; n < 4; ++n) bb[n] = bias2[head * 64 + n * 16 + l15];
#pragma unroll
        for (int m = 0; m < 8; ++m)
#pragma unroll
            for (int n = 0; n < 4; ++n) {
                int d = n * 16 + l15;
                int sl = m * 16 + (l4 << 2);
                bf16x4 pk = {(__bf16)(acc[m][n][0] + bb[n]), (__bf16)(acc[m][n][1] + bb[n]),
                             (__bf16)(acc[m][n][2] + bb[n]), (__bf16)(acc[m][n][3] + bb[n])};
                *(bf16x4*)(P + d * 128 + (sl ^ ((d & 7) << 3))) = pk;
            }
#pragma unroll
        for (int p = 0; p < 16; ++p) {
            int id = p * 64 + lane;
            int d = id >> 4, c8 = (id & 15) * 8;
            bf16x8 vv = *(const bf16x8*)(P + d * 128 + (c8 ^ ((d & 7) << 3)));
            *(bf16x8*)((bf16_t*)o2 + (((size_t)(b * 16 + head) * 64 + d) << 11) + sbase + c8) =
                vv;
        }
    }
}

// ------------- Pipelined 128x128 GEMM, wave=64x64 (C = A @ W^T) -------------
// 4-slot ring, lookahead 3, counted vmcnt. SPLIT=0: +bias +resid -> fp32.
// SPLIT=1: K-split via blockIdx.z, raw partial -> bf16.
template <int SPLIT>
__global__ __launch_bounds__(256, 2) void gemm128sq(
    const bf16_t* __restrict__ A, const bf16_t* __restrict__ Bw, int stride, int Ks,
    const float* __restrict__ bias, const float* __restrict__ resid,
    void* __restrict__ o0, void* __restrict__ o1) {
    __shared__ bf16_t L[4 * 8192];  // 4 slots x (A 128x32 + B 128x32) = 64KB
    const int t = threadIdx.x, lane = t & 63, w = t >> 6;
    const int wr = w >> 1, wc = w & 1;
    const int l15 = lane & 15, l4 = lane >> 4;
    const int bm = blockIdx.x, bn = blockIdx.y;
    const int NT = Ks >> 5;
    const size_t kofs = SPLIT ? (size_t)blockIdx.z * Ks : 0;
    const bf16_t* Ab = A + (size_t)bm * 128 * stride + kofs;
    const bf16_t* Bb = Bw + (size_t)bn * 128 * stride + kofs;
    const int srow = t >> 2, pcol = (t & 3) * 8;
    f32x4 acc[4][4] = {};

    auto STAGE = [&](int tt) {
        bf16_t* s = L + (tt & 3) * 8192;
        const int kb = tt * 32;
#pragma unroll
        for (int i = 0; i < 2; ++i) {
            int row = i * 64 + srow;
            int lcol = pcol ^ bswz(row);
            gload_lds16(Ab + (size_t)row * stride + kb + lcol, s + i * 2048 + t * 8);
            gload_lds16(Bb + (size_t)row * stride + kb + lcol, s + 4096 + i * 2048 + t * 8);
        }
    };

    STAGE(0); STAGE(1); STAGE(2);
    asm volatile("s_waitcnt vmcnt(8)" ::: "memory");
    __builtin_amdgcn_s_barrier();

    for (int tt = 0; tt < NT; ++tt) {
        bf16_t* s = L + (tt & 3) * 8192;
        bf16x8 af[4], bfr[4];
#pragma unroll
        for (int m = 0; m < 4; ++m) {
            int row = wr * 64 + m * 16 + l15;
            af[m] = *(const bf16x8*)(s + row * 32 + ((l4 * 8) ^ bswz(row)));
        }
#pragma unroll
        for (int n = 0; n < 4; ++n) {
            int row = wc * 64 + n * 16 + l15;
            bfr[n] = *(const bf16x8*)(s + 4096 + row * 32 + ((l4 * 8) ^ bswz(row)));
        }
        if (tt + 3 < NT) STAGE(tt + 3);
        __builtin_amdgcn_s_barrier();
        __builtin_amdgcn_s_setprio(1);
#pragma unroll
        for (int m = 0; m < 4; ++m)
#pragma unroll
            for (int n = 0; n < 4; ++n)
                acc[m][n] = __builtin_amdgcn_mfma_f32_16x16x32_bf16(af[m], bfr[n], acc[m][n],
                                                                   0, 0, 0);
        __builtin_amdgcn_s_setprio(0);
        if (tt + 3 < NT)
            asm volatile("s_waitcnt vmcnt(8)" ::: "memory");
        else if (tt + 2 < NT)
            asm volatile("s_waitcnt vmcnt(4)" ::: "memory");
        else
            asm volatile("s_waitcnt vmcnt(0)" ::: "memory");
        __builtin_amdgcn_s_barrier();
    }

#pragma unroll
    for (int m = 0; m < 4; ++m) {
        const int row0 = bm * 128 + wr * 64 + m * 16 + (l4 << 2);
#pragma unroll
        for (int n = 0; n < 4; ++n) {
            const int col = bn * 128 + wc * 64 + n * 16 + l15;
#pragma unroll
            for (int j = 0; j < 4; ++j) {
                const int row = row0 + j;
                if (SPLIT == 0) {
                    ((float*)o0)[(size_t)row * 1024 + col] =
                        resid[(size_t)row * 1024 + col] + acc[m][n][j] + bias[col];
                } else {
                    bf16_t* po = (bf16_t*)(blockIdx.z ? o1 : o0);
                    po[(size_t)row * 1024 + col] = (bf16_t)acc[m][n][j];
                }
            }
        }
    }
}

// ---- FFN2 combine: out = p0 + p1 + resid + bias (fp32), 4096x1024 ----------
__global__ __launch_bounds__(256) void ffn2_combine(
    const bf16_t* __restrict__ p0, const bf16_t* __restrict__ p1,
    const float* __restrict__ resid, const float* __restrict__ bias,
    float* __restrict__ out) {
    int i = blockIdx.x * 256 + threadIdx.x;  // float4 index, 1M total
    float4 r = ((const float4*)resid)[i];
    bf16x4 a = ((const bf16x4*)p0)[i];
    bf16x4 b = ((const bf16x4*)p1)[i];
    float4 bs = ((const float4*)bias)[i & 255];
    float4 o;
    o.x = r.x + (float)a.x + (float)b.x + bs.x;
    o.y = r.y + (float)a.y + (float)b.y + bs.y;
    o.z = r.z + (float)a.z + (float)b.z + bs.z;
    o.w = r.w + (float)a.w + (float)b.w + bs.w;
    ((float4*)out)[i] = o;
}

// --------------------------- Flash attention (R14) --------------------------
// Single kernel, grid 512, XCD-swizzled. 4 waves x 32 q-rows, KVBLK=128
// (16 iterations over 2048 keys). Reg-staged prefetch, single LDS buffer.
// 32x32x16 MFMA, swapped QK^T+PV, lane-local softmax (exp2 in place into sT),
// P in registers via cvt_pk + permlane32_swap.
__global__ __launch_bounds__(256, 2) void attn_kernel(const bf16_t* __restrict__ q,
                                                      const bf16_t* __restrict__ k,
                                                      const bf16_t* __restrict__ vt,
                                                      bf16_t* __restrict__ ctx) {
    __shared__ bf16_t Kl[128 * 64];  // 128 keys x 64 d, swz (128B rows)
    __shared__ bf16_t Vl[64 * 128];  // 64 d x 128 keys, swzV (256B rows)
    const int t = threadIdx.x, lane = t & 63, w = t >> 6;
    const int bid = blockIdx.x;
    const int xcd = bid & 7, j = bid >> 3;
    const int bh = xcd + ((j >> 4) << 3);
    const int qx = j & 15;
    const bf16_t* qg = q + (size_t)bh * 2048 * 64;
    const bf16_t* kg = k + (size_t)bh * 2048 * 64;
    const bf16_t* vg = vt + (size_t)bh * 64 * 2048;
    const int l31 = lane & 31, h = lane >> 5;
    const int rowl = w * 32 + l31;
    const int qrow = qx * 128 + rowl;
    // K staging: thread t -> rows {t>>3, +32, +64, +96}, chunk p = t&7
    const int kprow = t >> 3, kp8 = (t & 7) * 8;
    // V staging: thread t -> row t>>2, chunks {(t&3), +4, +8, +12}
    const int vrow = t >> 2, vc = t & 3;

    bf16x8 qf[4];
#pragma unroll
    for (int kd = 0; kd < 4; ++kd)
        qf[kd] = *(const bf16x8*)(qg + (size_t)qrow * 64 + kd * 16 + h * 8);

    f32x16 o0 = {}, o1 = {};
    float mi = -1e30f, li = 0.f;

    // prologue: stage tile 0 (128 keys) directly
    {
#pragma unroll
        for (int i = 0; i < 4; ++i) {
            bf16x8 kv = *(const bf16x8*)(kg + (size_t)(kprow + 32 * i) * 64 + kp8);
            *(bf16x8*)(Kl + swz(kprow + 32 * i, kp8)) = kv;
            bf16x8 vv = *(const bf16x8*)(vg + (size_t)vrow * 2048 + (vc + 4 * i) * 8);
            *(bf16x8*)(Vl + swzV(vrow, (vc + 4 * i) * 8)) = vv;
        }
    }

    const int NT = 16;
    for (int tt = 0; tt < NT; ++tt) {
        __syncthreads();  // staged tile visible
        // prefetch next tile into registers
        bf16x8 kr[4], vr[4];
        const bool more = (tt + 1) < NT;
        if (more) {
            const int kb = (tt + 1) * 128;
#pragma unroll
            for (int i = 0; i < 4; ++i) {
                kr[i] = *(const bf16x8*)(kg + (size_t)(kb + kprow + 32 * i) * 64 + kp8);
                vr[i] = *(const bf16x8*)(vg + (size_t)vrow * 2048 + kb + (vc + 4 * i) * 8);
            }
        }
        // QK^T swapped: sT[kb] = scores for keys kb*32..+32, cols q=lane&31
        f32x16 sT[4] = {};
        __builtin_amdgcn_s_setprio(1);
#pragma unroll
        for (int kb = 0; kb < 4; ++kb)
#pragma unroll
            for (int kd = 0; kd < 4; ++kd) {
                bf16x8 ka = *(const bf16x8*)(Kl + swz(kb * 32 + l31, kd * 16 + h * 8));
                sT[kb] = __builtin_amdgcn_mfma_f32_32x32x16_bf16(ka, qf[kd], sT[kb], 0, 0, 0);
            }
        __builtin_amdgcn_s_setprio(0);
        // lane-local tree max over 64 values + 1 shfl
        float pm[16];
#pragma unroll
        for (int i = 0; i < 16; ++i)
            pm[i] = fmaxf(fmaxf(sT[0][i], sT[1][i]), fmaxf(sT[2][i], sT[3][i]));
#pragma unroll
        for (int st = 8; st; st >>= 1)
#pragma unroll
            for (int i = 0; i < st; ++i) pm[i] = fmaxf(pm[i], pm[i + st]);
        float mx = fmaxf(pm[0], __shfl_xor(pm[0], 32));
        if (!__all(mx <= mi + 8.f)) {
            float mn = fmaxf(mi, mx);
            float al = __builtin_amdgcn_exp2f(mi - mn);
            mi = mn;
            li *= al;
            o0 *= al;
            o1 *= al;
        }
        // exp2 in place
#pragma unroll
        for (int kb = 0; kb < 4; ++kb)
#pragma unroll
            for (int i = 0; i < 16; ++i) sT[kb][i] = __builtin_amdgcn_exp2f(sT[kb][i] - mi);
        // lane-local tree sum
        float ps[16];
#pragma unroll
        for (int i = 0; i < 16; ++i)
            ps[i] = (sT[0][i] + sT[1][i]) + (sT[2][i] + sT[3][i]);
#pragma unroll
        for (int st = 8; st; st >>= 1)
#pragma unroll
            for (int i = 0; i < st; ++i) ps[i] += ps[i + st];
        li += ps[0] + __shfl_xor(ps[0], 32);
        // pack P into 8 PV B-frags (same per-32-key mapping as R8)
        bf16x8 pa[8];
#pragma unroll
        for (int kd = 0; kd < 8; ++kd) {
            const f32x16& e = sT[kd >> 1];
            const int R0l = 8 * (kd & 1);
            const int R0h = R0l + 4;
            unsigned U0 = cvtpk(e[R0l + 0], e[R0l + 1]);
            unsigned V0 = cvtpk(e[R0l + 2], e[R0l + 3]);
            unsigned U1 = cvtpk(e[R0h + 0], e[R0h + 1]);
            unsigned V1 = cvtpk(e[R0h + 2], e[R0h + 3]);
            uint32x2 ru = __builtin_amdgcn_permlane32_swap(U0, U1, false, false);
            uint32x2 rv = __builtin_amdgcn_permlane32_swap(V0, V1, false, false);
            uint32x4 pw = {ru.x, rv.x, ru.y, rv.y};
            pa[kd] = __builtin_bit_cast(bf16x8, pw);
        }
        // PV swapped: o rows = d, cols = q (8 key-slices of 16)
        __builtin_amdgcn_s_setprio(1);
#pragma unroll
        for (int kd = 0; kd < 8; ++kd) {
            bf16x8 va0 = *(const bf16x8*)(Vl + swzV(l31, kd * 16 + h * 8));
            bf16x8 va1 = *(const bf16x8*)(Vl + swzV(32 + l31, kd * 16 + h * 8));
            o0 = __builtin_amdgcn_mfma_f32_32x32x16_bf16(va0, pa[kd], o0, 0, 0, 0);
            o1 = __builtin_amdgcn_mfma_f32_32x32x16_bf16(va1, pa[kd], o1, 0, 0, 0);
        }
        __builtin_amdgcn_s_setprio(0);
        __syncthreads();  // all waves done reading Kl/Vl
        if (more) {
#pragma unroll
            for (int i = 0; i < 4; ++i) {
                *(bf16x8*)(Kl + swz(kprow + 32 * i, kp8)) = kr[i];
                *(bf16x8*)(Vl + swzV(vrow, (vc + 4 * i) * 8)) = vr[i];
            }
        }
    }
    // epilogue: direct ctx write (lane-local 1/l)
    float inv = 1.f / li;
    size_t base = ((size_t)(bh >> 4) * 2048 + qrow) * 1024 + (bh & 15) * 64;
#pragma unroll
    for (int g = 0; g < 4; ++g) {
        bf16x4 ov0 = {(__bf16)(o0[4 * g + 0] * inv), (__bf16)(o0[4 * g + 1] * inv),
                      (__bf16)(o0[4 * g + 2] * inv), (__bf16)(o0[4 * g + 3] * inv)};
        *(bf16x4*)(ctx + base + 8 * g + 4 * h) = ov0;
        bf16x4 ov1 = {(__bf16)(o1[4 * g + 0] * inv), (__bf16)(o1[4 * g + 1] * inv),
                      (__bf16)(o1[4 * g + 2] * inv), (__bf16)(o1[4 * g + 3] * inv)};
        *(bf16x4*)(ctx + base + 32 + 8 * g + 4 * h) = ov1;
    }
}

// ---------------------------------------------------------------------------
extern "C" void kernel_launch(void* const* d_in, const int* in_sizes, int n_in,
                              void* d_out, int out_size, void* d_ws, size_t ws_size,
                              hipStream_t stream) {
    const float* x = (const float*)d_in[0];
    const float* wq = (const float*)d_in[2];
    const float* bq = (const float*)d_in[3];
    const float* wk = (const float*)d_in[4];
    const float* bk = (const float*)d_in[5];
    const float* wv = (const float*)d_in[6];
    const float* bv = (const float*)d_in[7];
    const float* wo = (const float*)d_in[8];
    const float* bo = (const float*)d_in[9];
    const float* w1 = (const float*)d_in[10];
    const float* b1 = (const float*)d_in[11];
    const float* w2 = (const float*)d_in[12];
    const float* b2 = (const float*)d_in[13];
    const float* gamma1 = (const float*)d_in[14];
    const float* beta1 = (const float*)d_in[15];
    const float* gamma2 = (const float*)d_in[16];
    const float* beta2 = (const float*)d_in[17];

    char* ws = (char*)d_ws;
    bf16_t* wqkv = (bf16_t*)(ws + 0);
    bf16_t* wob = (bf16_t*)(ws + 6 * MB);
    bf16_t* w1b = (bf16_t*)(ws + 8 * MB);
    bf16_t* w2b = (bf16_t*)(ws + 16 * MB);
    bf16_t* xnb = (bf16_t*)(ws + 24 * MB);
    bf16_t* qb = (bf16_t*)(ws + 32 * MB);
    bf16_t* kb = (bf16_t*)(ws + 40 * MB);
    bf16_t* vtb = (bf16_t*)(ws + 48 * MB);
    bf16_t* ctxb = (bf16_t*)(ws + 56 * MB);
    float* x1 = (float*)(ws + 64 * MB);
    bf16_t* hb = (bf16_t*)(ws + 32 * MB);  // reuses q/k/vT/ctx (dead by FFN1)
    bf16_t* p0 = (bf16_t*)(ws + 0);        // FFN2 partial z=0 (wqkv/wob dead)
    bf16_t* p1 = (bf16_t*)(ws + 24 * MB);  // FFN2 partial z=1 (xnb dead)

    cvt_all<<<12288, 256, 0, stream>>>(wq, wk, wv, wo, w1, w2, wqkv, wob, w1b, w2b);

    // LN1
    ln_kernel<<<1024, 256, 0, stream>>>(x, xnb, gamma1, beta1);
    // QKV fused GEMM (256x256, N=3072)
    gemm256<0><<<dim3(16, 12), 512, 0, stream>>>(xnb, wqkv, 1024, bq, bk, bv, qb, kb, vtb);
    // attention (single kernel, XCD-swizzled, KVBLK=128)
    attn_kernel<<<512, 256, 0, stream>>>(qb, kb, vtb, ctxb);
    // out-proj + residual -> x1 (fp32)
    gemm128sq<0><<<dim3(32, 8), 256, 0, stream>>>(ctxb, wob, 1024, 1024, bo, x, x1, nullptr);
    // LN2
    ln_kernel<<<1024, 256, 0, stream>>>(x1, xnb, gamma2, beta2);
    // FFN1 + relu (256x256, N=4096)
    gemm256<1><<<dim3(16, 16), 512, 0, stream>>>(xnb, w1b, 1024, b1, nullptr, nullptr, hb,
                                                 nullptr, nullptr);
    // FFN2 K-split-2 -> bf16 partials, then combine with residual -> d_out
    gemm128sq<1><<<dim3(32, 8, 2), 256, 0, stream>>>(hb, w2b, 4096, 2048, nullptr, nullptr,
                                                     p0, p1);
    ffn2_combine<<<4096, 256, 0, stream>>>(p0, p1, x1, b2, (float*)d_out);
}